// Round 6
// baseline (249.678 us; speedup 1.0000x reference)
//
#include <hip/hip_runtime.h>

#define N_GENOMES 4000
#define N_SAMPLES 2048
#define N_GENES   28000
#define N_SEQS    16000
#define MAXW      16           // max genes per seq; P(exceed) ~1e-7
#define NSLICE    16           // sample slices of 128 samples each
#define SLICE_F2  64           // float2 per row-slice (128 samples)
#define ROW_F2    (N_SAMPLES / 2)   // 1024 float2 per full row
#define QCHUNK    128          // q's per block (32 per wave)
#define NCHUNK    (N_SEQS / QCHUNK) // 125
#define GRID      (2 * 8 * NCHUNK)  // 2000: two phases x 8 slices x 125 chunks

// ---------------- ELL build: seq -> up to MAXW (genome, pos) pairs ----------------

__global__ void ell_scatter_k(const int* __restrict__ seq_idx,
                              const int* __restrict__ genome_idx,
                              const float* __restrict__ pos,
                              int* __restrict__ counts,
                              int2* __restrict__ ell2) {
    int g = blockIdx.x * blockDim.x + threadIdx.x;
    if (g < N_GENES) {
        int q = seq_idx[g];
        int slot = atomicAdd(&counts[q], 1);
        if (slot < MAXW)
            ell2[q * MAXW + slot] = make_int2(genome_idx[g], __float_as_int(pos[g]));
    }
}

// ---------------- main: XCD-pinned sample slices, L2-resident gathers ------------
// out[q, s] = bias[q] * sum_{g : seq_idx[g]==q} A[gi,s] * 2^(1 - pos[g]*B[gi,s])
//
// r0/r4/r5 all pinned at ~90 us / 3.9 TB/s with 3 different schedules: the limiter
// is the 448 MB logical random-row gather missing the 4 MB per-XCD L2 (logical
// L2 throughput was already 6.4 TB/s = streaming ceiling). Fix locality, not
// schedule: partition samples into 16 slices of 128. A+B restricted to a slice =
// 4 MB = one XCD's L2. blockIdx%8 pins a slice to an XCD (round-robin dispatch);
// two sequential phases cover slices 0-7 then 8-15. Within a phase each XCD
// streams its 4 MB slice once, then gathers hit L2 (~6/7 reuse per genome row).
// Plain write-back stores only (r1: NT stores don't lane-merge -> 4x WRITE).

__global__ __launch_bounds__(256) void main_slice_k(
    const float* __restrict__ A, const float* __restrict__ B,
    const float* __restrict__ bias,
    const int* __restrict__ counts, const int2* __restrict__ ell2,
    float* __restrict__ out)
{
    const int G2    = GRID / 2;
    const int half  = blockIdx.x >= G2;
    const int b     = blockIdx.x - half * G2;
    const int slice = (b & 7) + (half << 3);   // 0..15; b%8 -> XCD id
    const int chunk = b >> 3;                  // 0..124
    const int wave  = threadIdx.x >> 6;
    const int lane  = threadIdx.x & 63;

    const int off = slice * SLICE_F2 + lane;   // float2 index within a row
    const float2* __restrict__ A2 = (const float2*)A;
    const float2* __restrict__ B2 = (const float2*)B;
    float2* __restrict__ O2 = (float2*)out;

    const int q0 = chunk * QCHUNK + wave * (QCHUNK / 4);
    const int q1 = q0 + QCHUNK / 4;            // 32 q's per wave, contiguous

    for (int q = q0; q < q1; ++q) {
        int cnt = counts[q];
        if (cnt > MAXW) cnt = MAXW;
        const int2* __restrict__ row = ell2 + q * MAXW;

        // Unconditional metadata preload (uniform -> scalar broadcast; slots
        // >= cnt hold poison but are never consumed as addresses).
        int2 e[4];
#pragma unroll
        for (int j = 0; j < 4; ++j) e[j] = row[j];

        // Batch of 4 genes: issue all 8 float2 gathers before any consumption.
        float2 av[4], bv[4];
#pragma unroll
        for (int j = 0; j < 4; ++j) {
            if (j < cnt) {
                av[j] = A2[(size_t)e[j].x * ROW_F2 + off];
                bv[j] = B2[(size_t)e[j].x * ROW_F2 + off];
            }
        }

        float accx = 0.f, accy = 0.f;
#pragma unroll
        for (int j = 0; j < 4; ++j) {
            if (j < cnt) {
                const float p = __int_as_float(e[j].y);
                accx += av[j].x * exp2f(1.0f - p * bv[j].x);
                accy += av[j].y * exp2f(1.0f - p * bv[j].y);
            }
        }

        // Rare tail (cnt > 4): ~3.4% of q's; metadata on demand (base+j <= 15).
#pragma unroll 1
        for (int base = 4; base < cnt; base += 4) {
            int2 et[4];
#pragma unroll
            for (int j = 0; j < 4; ++j) et[j] = row[base + j];
            float2 tav[4], tbv[4];
#pragma unroll
            for (int j = 0; j < 4; ++j) {
                if (base + j < cnt) {
                    tav[j] = A2[(size_t)et[j].x * ROW_F2 + off];
                    tbv[j] = B2[(size_t)et[j].x * ROW_F2 + off];
                }
            }
#pragma unroll
            for (int j = 0; j < 4; ++j) {
                if (base + j < cnt) {
                    const float p = __int_as_float(et[j].y);
                    accx += tav[j].x * exp2f(1.0f - p * tbv[j].x);
                    accy += tav[j].y * exp2f(1.0f - p * tbv[j].y);
                }
            }
        }

        const float bq = bias[q];
        float2 o; o.x = accx * bq; o.y = accy * bq;
        O2[(size_t)q * ROW_F2 + off] = o;      // 64 lanes x 8B = 512B contiguous
    }
}

// ---------------- launch ----------------

extern "C" void kernel_launch(void* const* d_in, const int* in_sizes, int n_in,
                              void* d_out, int out_size, void* d_ws, size_t ws_size,
                              hipStream_t stream) {
    const float* A          = (const float*)d_in[0];   // (4000, 2048)
    const float* B          = (const float*)d_in[1];   // (4000, 2048)
    const float* bias       = (const float*)d_in[2];   // (16000,)
    const float* pos        = (const float*)d_in[3];   // (28000,)
    const int*   genome_idx = (const int*)d_in[4];     // (28000,)
    const int*   seq_idx    = (const int*)d_in[5];     // (28000,)
    float*       out        = (float*)d_out;           // (16000, 2048)

    // ws layout: [counts: 16000 int][ell2: 16000*16 int2]
    int*  counts = (int*)d_ws;
    int2* ell2   = (int2*)((char*)d_ws + ((N_SEQS * sizeof(int) + 15) & ~15));

    hipMemsetAsync(counts, 0, N_SEQS * sizeof(int), stream);
    ell_scatter_k<<<(N_GENES + 255) / 256, 256, 0, stream>>>(seq_idx, genome_idx, pos,
                                                             counts, ell2);
    main_slice_k<<<GRID, 256, 0, stream>>>(A, B, bias, counts, ell2, out);
}